// Round 4
// baseline (515.395 us; speedup 1.0000x reference)
//
#include <hip/hip_runtime.h>
#include <cstdint>
#include <cstddef>

typedef unsigned short u16;
using f16x8 = __attribute__((ext_vector_type(8))) _Float16;
using f32x4 = __attribute__((ext_vector_type(4))) float;
using u16x4 = __attribute__((ext_vector_type(4))) unsigned short;

// float -> fp16 bit pattern (round-to-nearest-even via v_cvt_f16_f32)
__device__ __forceinline__ u16 f2h(float f) {
  union { _Float16 h; u16 u; } c;
  c.h = (_Float16)f;
  return c.u;
}

// async global->LDS, 16B per lane. LDS dest must be wave-uniform base; HW writes base + lane*16.
__device__ __forceinline__ void gl_lds16(const void* g, void* lds) {
  __builtin_amdgcn_global_load_lds(
      (const __attribute__((address_space(1))) void*)(uintptr_t)g,
      (__attribute__((address_space(3))) void*)(uint32_t)(uintptr_t)lds,
      16, 0, 0);
}

// counted vmcnt wait (inline asm, literal immediate)
template <int N> __device__ __forceinline__ void vmcnt_wait() {
  if constexpr (N == 0)      asm volatile("s_waitcnt vmcnt(0)" ::: "memory");
  else if constexpr (N == 3) asm volatile("s_waitcnt vmcnt(3)" ::: "memory");
  else if constexpr (N == 4) asm volatile("s_waitcnt vmcnt(4)" ::: "memory");
  else static_assert(N == 0, "unsupported vmcnt literal");
}

// raw workgroup barrier (no vmcnt(0) drain)
__device__ __forceinline__ void block_sync() {
  asm volatile("" ::: "memory");
  __builtin_amdgcn_s_barrier();
  asm volatile("" ::: "memory");
}

// ---------------------------------------------------------------------------
// Stage a ROWS x 32 u16 K-tile with SOURCE-side XOR swizzle (rule #21).
// ---------------------------------------------------------------------------
template <int ROWS>
__device__ __forceinline__ void stage32(const u16* g, int ldk, u16* lds, int t) {
#pragma unroll
  for (int i = 0; i < ROWS / 128; ++i) {
    const int s   = i * 512 + t;
    const int row = s >> 2;
    const int gc  = (s & 3) ^ ((s >> 3) & 3);
    gl_lds16(g + (size_t)row * ldk + gc * 8,
             lds + (size_t)(i * 512 + (t & ~63)) * 8);
  }
}

template <int NF>
__device__ __forceinline__ void compute_tile32(
    const u16* pA, const u16* pB, f32x4 (&acc)[8][NF],
    int wm, int wn, int lm, int cq)
{
  f16x8 bf[NF];
#pragma unroll
  for (int nf = 0; nf < NF; ++nf)
    bf[nf] = *(const f16x8*)(pB + (wn + nf * 16 + lm) * 32 + cq * 8);
#pragma unroll
  for (int mf = 0; mf < 8; ++mf) {
    f16x8 a0 = *(const f16x8*)(pA + (wm + mf * 16 + lm) * 32 + cq * 8);
#pragma unroll
    for (int nf = 0; nf < NF; ++nf)
      acc[mf][nf] = __builtin_amdgcn_mfma_f32_16x16x32_f16(a0, bf[nf], acc[mf][nf], 0, 0, 0);
  }
}

// ---------------------------------------------------------------------------
// bt-GEMM (K1/K2 only now), 256 x BN tile, BK=32, 4-buffer counted-vmcnt
// pipeline (validated round 3). Requires M%256==0, Ncols%BN==0, K%128==0.
// MODE 0: fp16 out (+bias).
// ---------------------------------------------------------------------------
template <int BN, int MODE>
__global__ __launch_bounds__(512, 2) void gemm32(
    const u16* __restrict__ A, const u16* __restrict__ Bt,
    void* __restrict__ Cv, const float* __restrict__ bias,
    int M, int Ncols, int K,
    long long strideA, long long strideB, long long strideC)
{
  constexpr int NF  = BN / 64;
  constexpr int LPT = 2 + BN / 128;

  __shared__ __align__(16) u16 sA0[256 * 32];
  __shared__ __align__(16) u16 sA1[256 * 32];
  __shared__ __align__(16) u16 sA2[256 * 32];
  __shared__ __align__(16) u16 sA3[256 * 32];
  __shared__ __align__(16) u16 sB0[BN * 32];
  __shared__ __align__(16) u16 sB1[BN * 32];
  __shared__ __align__(16) u16 sB2[BN * 32];
  __shared__ __align__(16) u16 sB3[BN * 32];

  const int bz = blockIdx.z;
  A  += (size_t)bz * strideA;
  Bt += (size_t)bz * strideB;

  const int m0 = blockIdx.y * 256;
  const int n0 = blockIdx.x * BN;
  const int t    = threadIdx.x;
  const int lane = t & 63;
  const int wave = t >> 6;
  const int wm   = (wave >> 2) * 128;
  const int wn   = (wave & 3) * (BN / 4);
  const int lm   = lane & 15;
  const int quad = lane >> 4;
  const int cq   = quad ^ ((lm >> 1) & 3);

  f32x4 acc[8][NF];
#pragma unroll
  for (int i = 0; i < 8; ++i)
#pragma unroll
    for (int j = 0; j < NF; ++j) acc[i][j] = f32x4{0.f, 0.f, 0.f, 0.f};

  const u16* Ag = A + (size_t)m0 * K;
  const u16* Bg = Bt + (size_t)n0 * K;

  const int nk = K >> 5;

  stage32<256>(Ag,      K, sA0, t);  stage32<BN>(Bg,      K, sB0, t);
  stage32<256>(Ag + 32, K, sA1, t);  stage32<BN>(Bg + 32, K, sB1, t);

  for (int kt = 0; kt < nk - 4; kt += 4) {
    vmcnt_wait<LPT>(); block_sync();
    stage32<256>(Ag + (size_t)(kt + 2) * 32, K, sA2, t);
    stage32<BN >(Bg + (size_t)(kt + 2) * 32, K, sB2, t);
    compute_tile32<NF>(sA0, sB0, acc, wm, wn, lm, cq);

    vmcnt_wait<LPT>(); block_sync();
    stage32<256>(Ag + (size_t)(kt + 3) * 32, K, sA3, t);
    stage32<BN >(Bg + (size_t)(kt + 3) * 32, K, sB3, t);
    compute_tile32<NF>(sA1, sB1, acc, wm, wn, lm, cq);

    vmcnt_wait<LPT>(); block_sync();
    stage32<256>(Ag + (size_t)(kt + 4) * 32, K, sA0, t);
    stage32<BN >(Bg + (size_t)(kt + 4) * 32, K, sB0, t);
    compute_tile32<NF>(sA2, sB2, acc, wm, wn, lm, cq);

    vmcnt_wait<LPT>(); block_sync();
    stage32<256>(Ag + (size_t)(kt + 5) * 32, K, sA1, t);
    stage32<BN >(Bg + (size_t)(kt + 5) * 32, K, sB1, t);
    compute_tile32<NF>(sA3, sB3, acc, wm, wn, lm, cq);
  }

  vmcnt_wait<LPT>(); block_sync();
  stage32<256>(Ag + (size_t)(nk - 2) * 32, K, sA2, t);
  stage32<BN >(Bg + (size_t)(nk - 2) * 32, K, sB2, t);
  compute_tile32<NF>(sA0, sB0, acc, wm, wn, lm, cq);

  vmcnt_wait<LPT>(); block_sync();
  stage32<256>(Ag + (size_t)(nk - 1) * 32, K, sA3, t);
  stage32<BN >(Bg + (size_t)(nk - 1) * 32, K, sB3, t);
  compute_tile32<NF>(sA1, sB1, acc, wm, wn, lm, cq);

  vmcnt_wait<LPT>(); block_sync();
  compute_tile32<NF>(sA2, sB2, acc, wm, wn, lm, cq);

  vmcnt_wait<0>(); block_sync();
  compute_tile32<NF>(sA3, sB3, acc, wm, wn, lm, cq);

  if (MODE == 0) {
    u16* C = (u16*)Cv + (size_t)bz * strideC;
#pragma unroll
    for (int nf = 0; nf < NF; ++nf) {
      const int col = n0 + wn + nf * 16 + lm;
      const float bv = bias ? bias[col] : 0.f;
#pragma unroll
      for (int mf = 0; mf < 8; ++mf)
#pragma unroll
        for (int r = 0; r < 4; ++r) {
          const int row = m0 + wm + mf * 16 + quad * 4 + r;
          C[(size_t)row * Ncols + col] = f2h(acc[mf][nf][r] + bv);
        }
    }
  } else {
    float* C = (float*)Cv + (size_t)bz * strideC;
#pragma unroll
    for (int nf = 0; nf < NF; ++nf) {
      const int col = n0 + wn + nf * 16 + lm;
#pragma unroll
      for (int mf = 0; mf < 8; ++mf)
#pragma unroll
        for (int r = 0; r < 4; ++r) {
          const int row = m0 + wm + mf * 16 + quad * 4 + r;
          C[(size_t)row * Ncols + col] = acc[mf][nf][r];
        }
    }
  }
}

// ---------------------------------------------------------------------------
// Fused K3+softmax+K5 (flash-style). Per batch bz, 64 Q-rows per block.
// Q = ha[bz] [2048][512] f16 (cached in regs), K = h[bz] (LDS-staged,
// source-swizzled), V-frags read direct from L2-resident hT[bz] [512][2048].
// O = elu( softmax_k(mask(Q.K^T)) . h ), f32 out.
// 8 waves: QK: wave w -> q-frag (w>>1), k-frag pair (w&1)*2+{0,1};
//          PV: wave w -> d-cols w*64..w*64+63.
// Online softmax with -1e30 mask sentinel; all-masked prefixes flush via f=0.
// ---------------------------------------------------------------------------
__global__ __launch_bounds__(512, 2) void fused_attn(
    const u16* __restrict__ Qg, const u16* __restrict__ Kg,
    const u16* __restrict__ Vt, const int* __restrict__ adj,
    float* __restrict__ out)
{
  constexpr int N = 2048, D = 512;
  __shared__ __align__(16) u16 sK[64 * 512];   // 64 KB, chunk16 ^ (row&7) swizzled
  __shared__ __align__(16) u16 sP[64 * 64];    // 8 KB, same swizzle
  __shared__ float sm[64], sl[64], sf[64];
  __shared__ float pmx[2][64], psm[2][64];

  const int bz = blockIdx.y;
  const int q0 = blockIdx.x * 64;
  const u16* Qb = Qg + ((size_t)bz * N + q0) * D;
  const u16* Kb = Kg + (size_t)bz * N * D;
  const u16* Vb = Vt + (size_t)bz * D * N;
  const int* Ab = adj + ((size_t)bz * N + q0) * N;
  float*     Ob = out + ((size_t)bz * N + q0) * D;

  const int t = threadIdx.x;
  const int lane = t & 63, wave = t >> 6;
  const int lm = lane & 15, quad = lane >> 4;
  const int qf  = wave >> 1;        // QK q-frag 0..3
  const int kf0 = (wave & 1) * 2;   // QK k-frag base

  // Q cache: A-frag layout (row = lane&15, k = quad*8+e), 16 d-steps of 32.
  f16x8 qreg[16];
#pragma unroll
  for (int s = 0; s < 16; ++s)
    qreg[s] = *(const f16x8*)(Qb + (size_t)(qf * 16 + lm) * D + s * 32 + quad * 8);

  if (t < 64) { sm[t] = -1e30f; sl[t] = 0.f; }

  f32x4 o_acc[4][4];
#pragma unroll
  for (int i = 0; i < 4; ++i)
#pragma unroll
    for (int j = 0; j < 4; ++j) o_acc[i][j] = f32x4{0.f, 0.f, 0.f, 0.f};

  __syncthreads();  // sm/sl init visible

  for (int kv = 0; kv < N; kv += 64) {
    // stage K-tile [64][512] u16; source chunk pre-swizzled: gc = c ^ (row&7)
#pragma unroll
    for (int i = 0; i < 8; ++i) {
      const int s = i * 512 + t;
      const int row = s >> 6, c = s & 63;
      gl_lds16(Kb + (size_t)(kv + row) * D + (size_t)((c ^ (row & 7)) * 8),
               sK + (size_t)(i * 512 + (t & ~63)) * 8);
    }
    // adjacency (output-layout rows): q = qf*16+quad*4+r, k = kv+(kf0+j)*16+lm
    int am[2][4];
#pragma unroll
    for (int j = 0; j < 2; ++j)
#pragma unroll
      for (int r = 0; r < 4; ++r)
        am[j][r] = Ab[(size_t)(qf * 16 + quad * 4 + r) * N + kv + (kf0 + j) * 16 + lm];
    // V-frags direct from L2 (hT rows = d-cols): bt-form B (row = d, k-contig)
    f16x8 vf[4][2];
#pragma unroll
    for (int df = 0; df < 4; ++df)
#pragma unroll
      for (int ks = 0; ks < 2; ++ks)
        vf[df][ks] = *(const f16x8*)(Vb + (size_t)(wave * 64 + df * 16 + lm) * N
                                        + kv + ks * 32 + quad * 8);

    __syncthreads();  // K-tile staged (drains vmcnt)

    // QK: S-frags for (qf, kf0..kf0+1)
    f32x4 sfr[2];
    sfr[0] = f32x4{0.f, 0.f, 0.f, 0.f};
    sfr[1] = f32x4{0.f, 0.f, 0.f, 0.f};
#pragma unroll
    for (int j = 0; j < 2; ++j) {
      const int krow = (kf0 + j) * 16 + lm;
#pragma unroll
      for (int s = 0; s < 16; ++s) {
        f16x8 kfr = *(const f16x8*)(sK + (size_t)krow * 512
                                       + (size_t)((((s * 4 + quad) ^ (lm & 7)) * 8)));
        sfr[j] = __builtin_amdgcn_mfma_f32_16x16x32_f16(qreg[s], kfr, sfr[j], 0, 0, 0);
      }
    }
    // mask + per-row partial max (reduce over 16 lm-lanes, then cross-wave)
    float vmax[4];
#pragma unroll
    for (int r = 0; r < 4; ++r) {
      sfr[0][r] = am[0][r] ? sfr[0][r] : -1e30f;
      sfr[1][r] = am[1][r] ? sfr[1][r] : -1e30f;
      vmax[r] = fmaxf(sfr[0][r], sfr[1][r]);
    }
#pragma unroll
    for (int r = 0; r < 4; ++r)
#pragma unroll
      for (int o = 1; o < 16; o <<= 1) vmax[r] = fmaxf(vmax[r], __shfl_xor(vmax[r], o));
    if (lm == 0)
#pragma unroll
      for (int r = 0; r < 4; ++r) pmx[wave & 1][qf * 16 + quad * 4 + r] = vmax[r];
    __syncthreads();

    if (t < 64) {
      const float mo = sm[t];
      const float mn = fmaxf(mo, fmaxf(pmx[0][t], pmx[1][t]));
      sm[t] = mn;
      sf[t] = __expf(mo - mn);  // 1 if unchanged; 0 flushes all-masked prefix
    }
    __syncthreads();

    // P = exp(S - m_new) -> sP (swizzled); per-row partial sums
    float vsum[4];
#pragma unroll
    for (int r = 0; r < 4; ++r) {
      const int row = qf * 16 + quad * 4 + r;
      const float mn = sm[row];
      const float e0 = __expf(sfr[0][r] - mn);
      const float e1 = __expf(sfr[1][r] - mn);
      vsum[r] = e0 + e1;
      const int rq = row & 7;
      sP[(size_t)row * 64 + (size_t)((((kf0    ) * 2 + (lm >> 3)) ^ rq) * 8) + (lm & 7)] = f2h(e0);
      sP[(size_t)row * 64 + (size_t)((((kf0 + 1) * 2 + (lm >> 3)) ^ rq) * 8) + (lm & 7)] = f2h(e1);
    }
#pragma unroll
    for (int r = 0; r < 4; ++r)
#pragma unroll
      for (int o = 1; o < 16; o <<= 1) vsum[r] += __shfl_xor(vsum[r], o);
    if (lm == 0)
#pragma unroll
      for (int r = 0; r < 4; ++r) psm[wave & 1][qf * 16 + quad * 4 + r] = vsum[r];
    __syncthreads();  // P visible + partial sums in

    if (t < 64) sl[t] = sl[t] * sf[t] + psm[0][t] + psm[1][t];

    // rescale O and accumulate PV (P from LDS, V from regs)
#pragma unroll
    for (int qi = 0; qi < 4; ++qi) {
      float fr[4];
#pragma unroll
      for (int r = 0; r < 4; ++r) fr[r] = sf[qi * 16 + quad * 4 + r];
#pragma unroll
      for (int df = 0; df < 4; ++df)
#pragma unroll
        for (int r = 0; r < 4; ++r) o_acc[qi][df][r] *= fr[r];
#pragma unroll
      for (int ks = 0; ks < 2; ++ks) {
        const int prow = qi * 16 + lm;  // A-frag layout: row = lane&15
        f16x8 pa = *(const f16x8*)(sP + (size_t)prow * 64
                                      + (size_t)((((ks * 4 + quad) ^ (lm & 7)) * 8)));
#pragma unroll
        for (int df = 0; df < 4; ++df)
          o_acc[qi][df] = __builtin_amdgcn_mfma_f32_16x16x32_f16(pa, vf[df][ks], o_acc[qi][df], 0, 0, 0);
      }
    }
    __syncthreads();  // all PV reads of sP / (next) sK overwrite safe
  }

  // epilogue: out = elu(O / l)
#pragma unroll
  for (int qi = 0; qi < 4; ++qi) {
    float il[4];
#pragma unroll
    for (int r = 0; r < 4; ++r) il[r] = 1.f / sl[qi * 16 + quad * 4 + r];
#pragma unroll
    for (int df = 0; df < 4; ++df)
#pragma unroll
      for (int r = 0; r < 4; ++r) {
        float v = o_acc[qi][df][r] * il[r];
        v = v > 0.f ? v : expm1f(v);
        Ob[(size_t)(qi * 16 + quad * 4 + r) * D + wave * 64 + df * 16 + lm] = v;
      }
  }
}

// ---------------------------------------------------------------------------
// 16-bit transpose per batch (z): in [R][C] -> out [C][R], 64x64 LDS tiles
// ---------------------------------------------------------------------------
__global__ __launch_bounds__(256) void transpose_u16(
    const u16* __restrict__ in, u16* __restrict__ outp, int R, int C)
{
  __shared__ u16 tile[64][65];
  const size_t base = (size_t)blockIdx.z * R * C;
  const int r0 = blockIdx.y * 64, c0 = blockIdx.x * 64;
  const int t = threadIdx.x;
  const int c = t & 63, rr = t >> 6;
#pragma unroll
  for (int i = 0; i < 16; ++i) {
    const int r = rr + i * 4;
    tile[r][c] = in[base + (size_t)(r0 + r) * C + c0 + c];
  }
  __syncthreads();
  const int rp = t & 63, cc = t >> 6;
#pragma unroll
  for (int i = 0; i < 16; ++i) {
    const int cq2 = cc + i * 4;
    outp[base + (size_t)(c0 + cq2) * R + r0 + rp] = tile[rp][cq2];
  }
}

__global__ __launch_bounds__(256) void cvt_f32_f16(
    const float* __restrict__ in, u16* __restrict__ outp, int n4)
{
  const int i = blockIdx.x * 256 + threadIdx.x;
  if (i >= n4) return;
  float4 v = ((const float4*)in)[i];
  u16x4 o; o[0] = f2h(v.x); o[1] = f2h(v.y); o[2] = f2h(v.z); o[3] = f2h(v.w);
  ((u16x4*)outp)[i] = o;
}

// out[j*R + i] = fp16(in[i*C + j])  (coalesced reads, tiny matrix)
__global__ __launch_bounds__(256) void transpose_cvt(
    const float* __restrict__ in, u16* __restrict__ outp, int R, int C)
{
  const int idx = blockIdx.x * 256 + threadIdx.x;
  const int i = idx / C, j = idx % C;
  outp[(size_t)j * R + i] = f2h(in[idx]);
}

// ---------------------------------------------------------------------------
extern "C" void kernel_launch(void* const* d_in, const int* in_sizes, int n_in,
                              void* d_out, int out_size, void* d_ws, size_t ws_size,
                              hipStream_t stream) {
  (void)in_sizes; (void)n_in; (void)out_size;
  const float* x    = (const float*)d_in[0];
  const int*   adj  = (const int*)d_in[1];
  const float* W    = (const float*)d_in[2];
  const float* bvec = (const float*)d_in[3];
  const float* attn = (const float*)d_in[4];
  float* out = (float*)d_out;

  constexpr int B = 8, N = 2048, D = 512;
  constexpr size_t MN = (size_t)B * N;  // 16384

  char* ws = (char*)d_ws;
  size_t off = 0;
  auto take = [&](size_t bytes) -> char* {
    char* p = ws + off;
    off += (bytes + 255) & ~(size_t)255;
    return p;
  };
  u16* xh   = (u16*)take(MN * D * 2);
  u16* Wh   = (u16*)take((size_t)D * D * 2);
  u16* attT = (u16*)take((size_t)D * D * 2);
  u16* h    = (u16*)take(MN * D * 2);
  u16* hT   = (u16*)take(MN * D * 2);
  u16* ha   = (u16*)take(MN * D * 2);
  if (ws_size < off) return;  // ws too small; fail validation cleanly

  // converts
  cvt_f32_f16<<<dim3((unsigned)(MN * D / 4 / 256)), 256, 0, stream>>>(x, xh, (int)(MN * D / 4));
  cvt_f32_f16<<<dim3(D * D / 4 / 256), 256, 0, stream>>>(W, Wh, D * D / 4);
  transpose_cvt<<<dim3(D * D / 256), 256, 0, stream>>>(attn, attT, D, D);

  // K1: h = xh . Wh^T + bias   [16384,512] x [512,512]
  gemm32<128, 0><<<dim3(D / 128, MN / 256, 1), 512, 0, stream>>>(
      xh, Wh, h, bvec, (int)MN, D, D, 0, 0, 0);
  // hT per batch: [2048,512] -> [512,2048]
  transpose_u16<<<dim3(D / 64, N / 64, B), 256, 0, stream>>>(h, hT, N, D);
  // K2: ha = h . attT^T
  gemm32<128, 0><<<dim3(D / 128, MN / 256, 1), 512, 0, stream>>>(
      h, attT, ha, nullptr, (int)MN, D, D, 0, 0, 0);

  // fused K3 + masked softmax + K5 (+ELU): 256 blocks, 1/CU
  fused_attn<<<dim3(N / 64, B), 512, 0, stream>>>(ha, h, hT, adj, out);
}